// Round 3
// baseline (465.800 us; speedup 1.0000x reference)
//
#include <hip/hip_runtime.h>

// Holt double-exponential smoothing along T for x[B=32, T=4096, C=512] fp32.
//   s[0] = x[0]; b[0] = x[1] - x[0]
//   s[t] = a*x[t] + (1-a)*(s[t-1] + b[t-1])
//   b[t] = B*(s[t] - s[t-1]) + (1-B)*b[t-1]
// out[t] = s[t].
//
// Parallel-in-T via chunked warm-up restart (transition spectral radius
// ~0.785 -> 64 warm-up steps shrink restart error by ~2e-7).
//
// R5: restore occupancy lost in the float2->float4 move. Evidence: float2 @
// 2048 waves (8 w/CU) ran ~117 us; float4 @ 1024 waves (4 w/CU) ran ~126 us
// at the SAME 32 KiB/CU loads-in-flight -> per-wave in-order vmcnt retire
// (nt stores interleaved with loads in one queue) stalls each wave; more
// waves = more independent queues. Fix: CHUNK 256->128 => NCHUNK=32, 1024
// blocks x 128 thr = 2048 waves (2/SIMD, 8 w/CU), 64 KiB/CU in flight,
// keeping float4's halved VMEM instruction count. Warm-up re-read grows
// 60->124 MB but is L2/L3-resident (FETCH 172 MB < 268 MB input already
// shows L3 absorption). WARM unchanged (one variable per round).
//
// Load pipeline: depth-8 register buffer, consuming buf[i&7] in order keeps
// 8 loads in flight; NITER uniform (192) across all chunks so unrolled buf
// indices stay static (no scratch); store guards are block-uniform.

#define ALPHA 0.8f
#define BETA 0.2f

typedef float f4 __attribute__((ext_vector_type(4)));

constexpr int T = 4096;
constexpr int C = 512;
constexpr int C4 = C / 4;           // float4 columns per (b,t) row = 128
constexpr int CHUNK = 128;          // output timesteps per chunk
constexpr int WARM = 64;            // warm-up timesteps
constexpr int NCHUNK = T / CHUNK;   // 32
constexpr int P = 8;                // load pipeline depth (power of 2)
constexpr int NITER = CHUNK + WARM; // 192, multiple of 8, uniform all chunks

__device__ __forceinline__ void holt_step(float xi, float& s, float& b) {
    float s_new = ALPHA * xi + (1.0f - ALPHA) * (s + b);
    b = BETA * (s_new - s) + (1.0f - BETA) * b;
    s = s_new;
}

__global__ __launch_bounds__(128) void holt_kernel(const float* __restrict__ x,
                                                   float* __restrict__ out) {
    const int c4 = threadIdx.x;        // 0..127 (float4 column)
    const int chunk = blockIdx.x;      // 0..NCHUNK-1
    const int b = blockIdx.y;          // 0..31

    const int t0 = chunk * CHUNK;
    const int tw = (chunk == 0) ? 0 : t0 - WARM;   // state-init timestep

    const f4* __restrict__ xin =
        reinterpret_cast<const f4*>(x) + (size_t)b * T * C4 + c4;
    f4* __restrict__ o =
        reinterpret_cast<f4*>(out) + (size_t)b * T * C4 + c4;

    // Init state at t = tw (exact for chunk 0, cold restart otherwise).
    f4 x0 = xin[(size_t)tw * C4];
    f4 x1 = xin[(size_t)(tw + 1) * C4];
    float sx = x0.x, sy = x0.y, sz = x0.z, sw = x0.w;
    float bx = x1.x - x0.x, by = x1.y - x0.y, bz = x1.z - x0.z, bw = x1.w - x0.w;

    if (chunk == 0) {
        o[0] = x0;                    // out[0] = s[0] = x[0]
    }

    const int t_start = tw + 1;       // first timestep consumed by the loop
    const int t_hi = t0 + CHUNK;      // store iff t0 <= t < t_hi

    // Prime the pipeline.
    f4 buf[P];
#pragma unroll
    for (int j = 0; j < P; ++j) {
        int t = t_start + j;
        t = (t < T) ? t : (T - 1);    // clamp (uniform, always in-bounds)
        buf[j] = xin[(size_t)t * C4];
    }

#pragma unroll 8
    for (int i = 0; i < NITER; ++i) {
        f4 xi = buf[i & (P - 1)];
        // Prefetch t + P into the slot just freed (clamped address so the
        // load is unconditional -> pipeline depth stays constant).
        int tp = t_start + i + P;
        tp = (tp < T) ? tp : (T - 1);
        buf[i & (P - 1)] = xin[(size_t)tp * C4];

        holt_step(xi.x, sx, bx);
        holt_step(xi.y, sy, by);
        holt_step(xi.z, sz, bz);
        holt_step(xi.w, sw, bw);

        const int t = t_start + i;    // block-uniform
        if (t >= t0 && t < t_hi) {
            f4 v;
            v.x = sx; v.y = sy; v.z = sz; v.w = sw;
            __builtin_nontemporal_store(v, &o[(size_t)t * C4]);
        }
    }
}

extern "C" void kernel_launch(void* const* d_in, const int* in_sizes, int n_in,
                              void* d_out, int out_size, void* d_ws, size_t ws_size,
                              hipStream_t stream) {
    const float* x = (const float*)d_in[0];
    float* out = (float*)d_out;
    dim3 grid(NCHUNK, 32);   // 32 chunks x 32 batches = 1024 blocks, 2 waves each
    holt_kernel<<<grid, 128, 0, stream>>>(x, out);
}

// Round 4
// 450.539 us; speedup vs baseline: 1.0339x; 1.0339x over previous
//
#include <hip/hip_runtime.h>

// Holt double-exponential smoothing along T for x[B=32, T=4096, C=512] fp32.
//   s[0] = x[0]; b[0] = x[1] - x[0]
//   s[t] = a*x[t] + (1-a)*(s[t-1] + b[t-1])
//   b[t] = B*(s[t] - s[t-1]) + (1-B)*b[t-1]
// out[t] = s[t].
//
// Parallel-in-T via chunked warm-up restart (transition spectral radius
// ~0.785 -> 64 warm-up steps shrink restart error by ~2e-7).
//
// R6: remove NONTEMPORAL stores (one variable vs measured R4 config).
// History: R2 (float2, plain stores) ~117 us; R4 (float4 + nt) 174 us;
// R5 (float4 + nt, 2x occupancy) 178.5 us. Occupancy didn't help -> the
// regression is per-wave: vmcnt retires IN ORDER, and an nt store's ack
// comes from HBM-depth (~900 cyc) instead of L2 (~200 cyc), blocking
// retirement of every younger load in the same wave's queue. Steady state
// alternates load/store, so the depth-8 load pipeline collapses to
// store-retire latency per iteration. Plain stores ack at L2 and drain
// lazily; write stream is full-line coalesced so L2 pollution is minor
// (warm re-reads are L3-resident regardless).
//
// Config: float4 streaming, CHUNK=256 (R4 beat R5's CHUNK=128 on warm-up
// re-fetch), 128-thr blocks, depth-8 register load pipeline, NITER uniform
// (320) so unrolled buf indices stay static; store guards block-uniform.

#define ALPHA 0.8f
#define BETA 0.2f

typedef float f4 __attribute__((ext_vector_type(4)));

constexpr int T = 4096;
constexpr int C = 512;
constexpr int C4 = C / 4;           // float4 columns per (b,t) row = 128
constexpr int CHUNK = 256;          // output timesteps per chunk
constexpr int WARM = 64;            // warm-up timesteps
constexpr int NCHUNK = T / CHUNK;   // 16
constexpr int P = 8;                // load pipeline depth (power of 2)
constexpr int NITER = CHUNK + WARM; // 320, multiple of 8, uniform all chunks

__device__ __forceinline__ void holt_step(float xi, float& s, float& b) {
    float s_new = ALPHA * xi + (1.0f - ALPHA) * (s + b);
    b = BETA * (s_new - s) + (1.0f - BETA) * b;
    s = s_new;
}

__global__ __launch_bounds__(128) void holt_kernel(const float* __restrict__ x,
                                                   float* __restrict__ out) {
    const int c4 = threadIdx.x;        // 0..127 (float4 column)
    const int chunk = blockIdx.x;      // 0..NCHUNK-1
    const int b = blockIdx.y;          // 0..31

    const int t0 = chunk * CHUNK;
    const int tw = (chunk == 0) ? 0 : t0 - WARM;   // state-init timestep

    const f4* __restrict__ xin =
        reinterpret_cast<const f4*>(x) + (size_t)b * T * C4 + c4;
    f4* __restrict__ o =
        reinterpret_cast<f4*>(out) + (size_t)b * T * C4 + c4;

    // Init state at t = tw (exact for chunk 0, cold restart otherwise).
    f4 x0 = xin[(size_t)tw * C4];
    f4 x1 = xin[(size_t)(tw + 1) * C4];
    float sx = x0.x, sy = x0.y, sz = x0.z, sw = x0.w;
    float bx = x1.x - x0.x, by = x1.y - x0.y, bz = x1.z - x0.z, bw = x1.w - x0.w;

    if (chunk == 0) {
        o[0] = x0;                    // out[0] = s[0] = x[0]
    }

    const int t_start = tw + 1;       // first timestep consumed by the loop
    const int t_hi = t0 + CHUNK;      // store iff t0 <= t < t_hi

    // Prime the pipeline.
    f4 buf[P];
#pragma unroll
    for (int j = 0; j < P; ++j) {
        int t = t_start + j;
        t = (t < T) ? t : (T - 1);    // clamp (uniform, always in-bounds)
        buf[j] = xin[(size_t)t * C4];
    }

#pragma unroll 8
    for (int i = 0; i < NITER; ++i) {
        f4 xi = buf[i & (P - 1)];
        // Prefetch t + P into the slot just freed (clamped address so the
        // load is unconditional -> pipeline depth stays constant).
        int tp = t_start + i + P;
        tp = (tp < T) ? tp : (T - 1);
        buf[i & (P - 1)] = xin[(size_t)tp * C4];

        holt_step(xi.x, sx, bx);
        holt_step(xi.y, sy, by);
        holt_step(xi.z, sz, bz);
        holt_step(xi.w, sw, bw);

        const int t = t_start + i;    // block-uniform
        if (t >= t0 && t < t_hi) {
            f4 v;
            v.x = sx; v.y = sy; v.z = sz; v.w = sw;
            o[(size_t)t * C4] = v;
        }
    }
}

extern "C" void kernel_launch(void* const* d_in, const int* in_sizes, int n_in,
                              void* d_out, int out_size, void* d_ws, size_t ws_size,
                              hipStream_t stream) {
    const float* x = (const float*)d_in[0];
    float* out = (float*)d_out;
    dim3 grid(NCHUNK, 32);   // 16 chunks x 32 batches = 512 blocks, 2 waves each
    holt_kernel<<<grid, 128, 0, stream>>>(x, out);
}